// Round 1
// baseline (1134.140 us; speedup 1.0000x reference)
//
#include <hip/hip_runtime.h>
#include <cstddef>

#define N_NODES 12288
#define SIG     2048
#define C1N     16
#define L1N     1024
#define C2N     32
#define L2N     512
#define F0      64
#define F1      128
#define NEDGE   196608
#define NGRAPH  1024

// ---------------------------------------------------------------- encoder
// one block (256 threads) per node: conv1 -> relu -> conv2 -> relu -> mean -> linear
__global__ __launch_bounds__(256) void k_encoder(
    const float* __restrict__ x_raw,
    const float* __restrict__ conv1_w, const float* __restrict__ conv1_b,
    const float* __restrict__ conv2_w, const float* __restrict__ conv2_b,
    const float* __restrict__ lin_w,   const float* __restrict__ lin_b,
    float* __restrict__ h0)
{
    __shared__ float  xs[2064];          // x[i] at xs[8+i], zero pads both sides
    __shared__ float  c1s[C1N][520];     // chunked conv1 output (slot s = pos 2*qbase-2+s)
    __shared__ float4 wts4[C1N*5*8];     // conv2 weights: [(ic*5+t)*32 + oc], float4 over oc
    __shared__ float  w1s[C1N*8];        // conv1: 7 weights + bias per channel
    __shared__ float  red[4][C2N];
    __shared__ float  mean_s[C2N];

    float* wts = (float*)wts4;
    const int tid  = threadIdx.x;
    const int node = blockIdx.x;

    // stage conv2 weights transposed: wts[(ic*5+t)*32 + oc] = conv2_w[oc*80 + ic*5 + t]
    for (int i = tid; i < C2N*C1N*5; i += 256) {
        int oc = i / 80;
        int r  = i - oc * 80;            // r = ic*5+t
        wts[r*32 + oc] = conv2_w[i];
    }
    for (int i = tid; i < C1N*8; i += 256) {
        int ic = i >> 3, t = i & 7;
        w1s[i] = (t < 7) ? conv1_w[ic*7 + t] : conv1_b[ic];
    }
    {
        const float* xrow = x_raw + (size_t)node * SIG;
        for (int i = tid; i < 2064; i += 256) {
            int xi = i - 8;
            xs[i] = (xi >= 0 && xi < SIG) ? xrow[xi] : 0.f;
        }
    }
    __syncthreads();

    float msum[C2N];
    #pragma unroll
    for (int oc = 0; oc < C2N; ++oc) msum[oc] = 0.f;

    for (int ph = 0; ph < 2; ++ph) {
        const int qbase = ph * 256;

        // conv1 chunk: slots s in [0,516), c1 position pos = 2*qbase - 2 + s
        for (int idx = tid; idx < C1N*516; idx += 256) {
            int ic  = idx / 516;
            int s   = idx - ic * 516;
            int pos = 2*qbase - 2 + s;
            float v = 0.f;
            if ((unsigned)pos < (unsigned)L1N) {
                const float* w  = &w1s[ic << 3];
                const float* xp = &xs[2*pos + 5];   // x index 2*pos-3+t at xs[2*pos+5+t]
                float a = w[7];
                #pragma unroll
                for (int t = 0; t < 7; ++t) a = fmaf(xp[t], w[t], a);
                v = fmaxf(a, 0.f);
            }
            c1s[ic][s] = v;
        }
        __syncthreads();

        // conv2 at q = qbase + tid: needs c1 slots 2*tid .. 2*tid+4
        float acc[C2N];
        #pragma unroll
        for (int oc = 0; oc < C2N; ++oc) acc[oc] = conv2_b[oc];

        for (int ic = 0; ic < C1N; ++ic) {
            float v[5];
            #pragma unroll
            for (int k = 0; k < 5; ++k) v[k] = c1s[ic][2*tid + k];
            #pragma unroll
            for (int t = 0; t < 5; ++t) {
                float vv = v[t];
                const float4* wrow = wts4 + (ic*5 + t)*8;
                #pragma unroll
                for (int o4 = 0; o4 < 8; ++o4) {
                    float4 w = wrow[o4];          // wave-uniform broadcast read
                    acc[o4*4+0] = fmaf(vv, w.x, acc[o4*4+0]);
                    acc[o4*4+1] = fmaf(vv, w.y, acc[o4*4+1]);
                    acc[o4*4+2] = fmaf(vv, w.z, acc[o4*4+2]);
                    acc[o4*4+3] = fmaf(vv, w.w, acc[o4*4+3]);
                }
            }
        }
        #pragma unroll
        for (int oc = 0; oc < C2N; ++oc) msum[oc] += fmaxf(acc[oc], 0.f);
        __syncthreads();   // before next phase overwrites c1s
    }

    // reduce msum over 256 threads (64-lane wave shuffles, then LDS)
    const int lane = tid & 63, wv = tid >> 6;
    #pragma unroll
    for (int oc = 0; oc < C2N; ++oc) {
        float s = msum[oc];
        s += __shfl_down(s, 32);
        s += __shfl_down(s, 16);
        s += __shfl_down(s, 8);
        s += __shfl_down(s, 4);
        s += __shfl_down(s, 2);
        s += __shfl_down(s, 1);
        msum[oc] = s;
    }
    if (lane == 0) {
        #pragma unroll
        for (int oc = 0; oc < C2N; ++oc) red[wv][oc] = msum[oc];
    }
    __syncthreads();
    if (tid < C2N) {
        float s = red[0][tid] + red[1][tid] + red[2][tid] + red[3][tid];
        mean_s[tid] = s * (1.f / 512.f);
    }
    __syncthreads();

    // linear 32 -> 64
    if (tid < F0) {
        float a = lin_b[tid];
        #pragma unroll
        for (int ic = 0; ic < C2N; ++ic)
            a = fmaf(mean_s[ic], lin_w[ic*F0 + tid], a);
        h0[(size_t)node * F0 + tid] = a;
    }
}

// ---------------------------------------------------------------- degree
__global__ __launch_bounds__(256) void k_count(const int* __restrict__ dst,
                                               int* __restrict__ deg)
{
    int e = blockIdx.x * 256 + threadIdx.x;
    if (e < NEDGE) atomicAdd(&deg[dst[e]], 1);
}

__global__ __launch_bounds__(256) void k_dis(const int* __restrict__ deg,
                                             float* __restrict__ dis,
                                             float* __restrict__ invd)
{
    int n = blockIdx.x * 256 + threadIdx.x;
    if (n < N_NODES) {
        float d = (float)(deg[n] + 1);   // +1 self loop
        dis[n]  = rsqrtf(d);
        invd[n] = 1.f / d;
    }
}

// ---------------------------------------------------------------- h @ W (K -> 128)
__global__ __launch_bounds__(256) void k_gemm(const float* __restrict__ h,
                                              const float* __restrict__ W,
                                              float* __restrict__ out, int K)
{
    __shared__ float hs[2][F1];
    const int tid = threadIdx.x;
    const int n0  = blockIdx.x * 2;
    const int r   = tid >> 7;
    const int j   = tid & 127;

    if (tid < 2*K) {
        int nn = (tid >= K) ? 1 : 0;
        int kk = tid - nn * K;
        hs[nn][kk] = h[(size_t)(n0 + nn) * K + kk];
    }
    __syncthreads();

    float a = 0.f;
    for (int k = 0; k < K; ++k)
        a = fmaf(hs[r][k], W[k*F1 + j], a);
    out[(size_t)(n0 + r) * F1 + j] = a;
}

// ---------------------------------------------------------------- edge aggregation (push, atomics)
__global__ __launch_bounds__(256) void k_edge(const int* __restrict__ src,
                                              const int* __restrict__ dst,
                                              const float* __restrict__ dis,
                                              const float* __restrict__ tmp,
                                              float* __restrict__ agg)
{
    int t = blockIdx.x * 256 + threadIdx.x;
    int e = t >> 7;
    int f = t & 127;
    if (e < NEDGE) {
        int s = src[e], d = dst[e];
        float nv = dis[s] * dis[d];
        atomicAdd(&agg[(size_t)d * F1 + f], tmp[(size_t)s * F1 + f] * nv);
    }
}

// ---------------------------------------------------------------- self term + bias + relu
__global__ __launch_bounds__(256) void k_finish(const float* __restrict__ agg,
                                                const float* __restrict__ tmp,
                                                const float* __restrict__ invd,
                                                const float* __restrict__ b,
                                                float* __restrict__ hout)
{
    int t = blockIdx.x * 256 + threadIdx.x;   // < N_NODES*F1
    int n = t >> 7, f = t & 127;
    float v = agg[t] + tmp[t] * invd[n] + b[f];
    hout[t] = fmaxf(v, 0.f);
}

// ---------------------------------------------------------------- mean pool per graph
__global__ __launch_bounds__(256) void k_pool(const float* __restrict__ h2,
                                              const int* __restrict__ batch,
                                              float* __restrict__ pooled,
                                              float* __restrict__ cnt)
{
    int t = blockIdx.x * 256 + threadIdx.x;   // < N_NODES*F1
    int n = t >> 7, f = t & 127;
    int g = batch[n];
    atomicAdd(&pooled[(size_t)g * F1 + f], h2[t]);
    if (f == 0) atomicAdd(&cnt[g], 1.f);
}

// ---------------------------------------------------------------- final FC 128 -> 5
__global__ __launch_bounds__(128) void k_final(const float* __restrict__ pooled,
                                               const float* __restrict__ cnt,
                                               const float* __restrict__ fc_w,
                                               const float* __restrict__ fc_b,
                                               float* __restrict__ out)
{
    __shared__ float ps[F1];
    const int g = blockIdx.x, tid = threadIdx.x;
    float inv = 1.f / fmaxf(cnt[g], 1.f);
    ps[tid] = pooled[g*F1 + tid] * inv;
    __syncthreads();
    if (tid < 5) {
        float a = fc_b[tid];
        for (int f = 0; f < F1; ++f) a = fmaf(ps[f], fc_w[f*5 + tid], a);
        out[g*5 + tid] = a;
    }
}

// ---------------------------------------------------------------- launch
extern "C" void kernel_launch(void* const* d_in, const int* in_sizes, int n_in,
                              void* d_out, int out_size, void* d_ws, size_t ws_size,
                              hipStream_t stream)
{
    const float* x_raw = (const float*)d_in[0];
    const float* c1w   = (const float*)d_in[1];
    const float* c1b   = (const float*)d_in[2];
    const float* c2w   = (const float*)d_in[3];
    const float* c2b   = (const float*)d_in[4];
    const float* lw    = (const float*)d_in[5];
    const float* lb    = (const float*)d_in[6];
    const float* g1w   = (const float*)d_in[7];
    const float* g1b   = (const float*)d_in[8];
    const float* g2w   = (const float*)d_in[9];
    const float* g2b   = (const float*)d_in[10];
    const float* fcw   = (const float*)d_in[11];
    const float* fcb   = (const float*)d_in[12];
    const int*   ei    = (const int*)d_in[13];
    const int*   batch = (const int*)d_in[14];
    const int* src = ei;
    const int* dst = ei + NEDGE;

    float* ws = (float*)d_ws;
    // workspace layout (float offsets)
    float* h0     = ws + 0;             // 786432
    float* tmp    = ws + 786432;        // 1572864
    float* agg    = ws + 2359296;       // 1572864
    float* h1     = ws + 3932160;       // 1572864
    float* h2     = ws + 5505024;       // 1572864
    float* dis    = ws + 7077888;       // 12288
    float* invd   = ws + 7090176;       // 12288
    float* pooled = ws + 7102464;       // 131072
    float* cnt    = ws + 7233536;       // 1024
    int*   deg    = (int*)(ws + 7234560); // 12288 ints

    float* out = (float*)d_out;

    hipMemsetAsync(deg, 0, N_NODES * sizeof(int), stream);
    k_encoder<<<N_NODES, 256, 0, stream>>>(x_raw, c1w, c1b, c2w, c2b, lw, lb, h0);
    k_count<<<(NEDGE + 255) / 256, 256, 0, stream>>>(dst, deg);
    k_dis<<<(N_NODES + 255) / 256, 256, 0, stream>>>(deg, dis, invd);

    // GCN layer 1
    k_gemm<<<N_NODES / 2, 256, 0, stream>>>(h0, g1w, tmp, F0);
    hipMemsetAsync(agg, 0, (size_t)N_NODES * F1 * sizeof(float), stream);
    k_edge<<<NEDGE / 2, 256, 0, stream>>>(src, dst, dis, tmp, agg);
    k_finish<<<N_NODES * F1 / 256, 256, 0, stream>>>(agg, tmp, invd, g1b, h1);

    // GCN layer 2
    k_gemm<<<N_NODES / 2, 256, 0, stream>>>(h1, g2w, tmp, F1);
    hipMemsetAsync(agg, 0, (size_t)N_NODES * F1 * sizeof(float), stream);
    k_edge<<<NEDGE / 2, 256, 0, stream>>>(src, dst, dis, tmp, agg);
    k_finish<<<N_NODES * F1 / 256, 256, 0, stream>>>(agg, tmp, invd, g2b, h2);

    // pool + fc
    hipMemsetAsync(pooled, 0, (size_t)(NGRAPH * F1 + NGRAPH) * sizeof(float), stream);
    k_pool<<<N_NODES * F1 / 256, 256, 0, stream>>>(h2, batch, pooled, cnt);
    k_final<<<NGRAPH, 128, 0, stream>>>(pooled, cnt, fcw, fcb, out);
}